// Round 1
// baseline (3630.733 us; speedup 1.0000x reference)
//
#include <hip/hip_runtime.h>

#define CC 256
#define SS 1024
#define DD 128
#define NH 2
#define DH 64
#define KK 4
#define CI_CHUNK 64

// qk[c][n] = sum_d Wk[c, n*64+d] * q[n, d]
__global__ void qk_kernel(const float* __restrict__ Wk, const float* __restrict__ q,
                          float* __restrict__ qk) {
  int t = blockIdx.x * blockDim.x + threadIdx.x;
  if (t >= CC * NH) return;
  int c = t >> 1, n = t & 1;
  float s = 0.f;
  for (int d = 0; d < DH; ++d) s += Wk[c * DD + n * DH + d] * q[n * DH + d];
  qk[c * NH + n] = s;
}

// scores[b][n][s] = (x[b,s,:] . qk[:,n]) / 8   (one wave per pixel)
__global__ void scores_kernel(const float* __restrict__ x, const float* __restrict__ qk,
                              float* __restrict__ attn) {
  int wave = threadIdx.x >> 6, lane = threadIdx.x & 63;
  int pix = blockIdx.x * 4 + wave;  // [0, 32768)
  int b = pix >> 10, s = pix & 1023;
  const float4 xv = *(const float4*)(x + (size_t)pix * CC + lane * 4);
  float d0 = 0.f, d1 = 0.f;
  const float* xp = (const float*)&xv;
#pragma unroll
  for (int j = 0; j < 4; ++j) {
    float xc = xp[j];
    d0 += xc * qk[(lane * 4 + j) * NH + 0];
    d1 += xc * qk[(lane * 4 + j) * NH + 1];
  }
#pragma unroll
  for (int m = 32; m >= 1; m >>= 1) {
    d0 += __shfl_xor(d0, m, 64);
    d1 += __shfl_xor(d1, m, 64);
  }
  if (lane == 0) {
    attn[((size_t)b * NH + 0) * SS + s] = d0 * 0.125f;
    attn[((size_t)b * NH + 1) * SS + s] = d1 * 0.125f;
  }
}

// in-place softmax over s for each (b, n) row  (block per row, 256 thr x 4 vals)
__global__ void softmax_kernel(float* __restrict__ attn) {
  __shared__ float red[4];
  float* p = attn + (size_t)blockIdx.x * SS;
  int tid = threadIdx.x;
  float4 v = *(float4*)(p + tid * 4);
  float m = fmaxf(fmaxf(v.x, v.y), fmaxf(v.z, v.w));
#pragma unroll
  for (int sh = 32; sh >= 1; sh >>= 1) m = fmaxf(m, __shfl_xor(m, sh, 64));
  if ((tid & 63) == 0) red[tid >> 6] = m;
  __syncthreads();
  m = fmaxf(fmaxf(red[0], red[1]), fmaxf(red[2], red[3]));
  float4 e;
  e.x = expf(v.x - m); e.y = expf(v.y - m);
  e.z = expf(v.z - m); e.w = expf(v.w - m);
  float s = e.x + e.y + e.z + e.w;
#pragma unroll
  for (int sh = 32; sh >= 1; sh >>= 1) s += __shfl_xor(s, sh, 64);
  __syncthreads();
  if ((tid & 63) == 0) red[tid >> 6] = s;
  __syncthreads();
  s = red[0] + red[1] + red[2] + red[3];
  float inv = 1.f / s;
  e.x *= inv; e.y *= inv; e.z *= inv; e.w *= inv;
  *(float4*)(p + tid * 4) = e;
}

// rowscale[b][s] = 1 + 0.5*(attn0+attn1) * S * softplus(alpha)
__global__ void rowscale_kernel(const float* __restrict__ attn, const float* __restrict__ alpha,
                                float* __restrict__ rowscale) {
  int i = blockIdx.x * 256 + threadIdx.x;  // 32768
  int b = i >> 10, s = i & 1023;
  float al = alpha[0];
  float a = (al > 20.f) ? al : log1pf(expf(al));
  float am = 0.5f * (attn[((size_t)b * NH) * SS + s] + attn[((size_t)b * NH + 1) * SS + s]);
  rowscale[i] = 1.f + am * (float)SS * a;
}

// xa[b][n][c] = sum_s attn[b][n][s] * x[b][s][c]
__global__ void xa_kernel(const float* __restrict__ x, const float* __restrict__ attn,
                          float* __restrict__ xa) {
  int b = blockIdx.x, c = threadIdx.x;
  float acc0 = 0.f, acc1 = 0.f;
  const float* a0 = attn + (size_t)b * NH * SS;
  const float* a1 = a0 + SS;
  const float* xb = x + (size_t)b * SS * CC + c;
  for (int s = 0; s < SS; ++s) {
    float xv = xb[(size_t)s * CC];
    acc0 += a0[s] * xv;
    acc1 += a1[s] * xv;
  }
  xa[((size_t)b * NH + 0) * CC + c] = acc0;
  xa[((size_t)b * NH + 1) * CC + c] = acc1;
}

// pooled -> logits -> routing (softmax / top-2 / allowed update), block per batch
__global__ void route_kernel(const float* __restrict__ xa, const float* __restrict__ Wv,
                             const float* __restrict__ Wmlp, float* __restrict__ allowed,
                             int* __restrict__ selE, float* __restrict__ selW, int step) {
  __shared__ float pooled[DD];
  __shared__ float lg[KK];
  int b = blockIdx.x, tid = threadIdx.x;  // 128 threads
  int n = tid >> 6;
  float acc = 0.f;
  const float* xr = xa + ((size_t)b * NH + n) * CC;
  for (int c = 0; c < CC; ++c) acc += xr[c] * Wv[(size_t)c * DD + tid];
  pooled[tid] = acc;
  __syncthreads();
  if (tid < KK) {
    float s = 0.f;
    for (int d = 0; d < DD; ++d) s += pooled[d] * Wmlp[d * KK + tid];
    lg[tid] = s;
  }
  __syncthreads();
  if (tid == 0) {
    float al[KK];
    if (step == 0) {
      for (int k = 0; k < KK; ++k) al[k] = 1.f;
    } else {
      for (int k = 0; k < KK; ++k) al[k] = allowed[b * KK + k];
    }
    float ml[KK];
    for (int k = 0; k < KK; ++k)
      ml[k] = (al[k] > 0.5f) ? lg[k] * (1.f / 1.5f) : (-1e9f) * (1.f / 1.5f);
    float m = ml[0];
    for (int k = 1; k < KK; ++k) m = fmaxf(m, ml[k]);
    float e[KK], ssum = 0.f;
    for (int k = 0; k < KK; ++k) { e[k] = expf(ml[k] - m); ssum += e[k]; }
    float w[KK];
    for (int k = 0; k < KK; ++k) w[k] = e[k] / ssum;
    int i0 = 0;
    for (int k = 1; k < KK; ++k) if (w[k] > w[i0]) i0 = k;
    int i1 = -1;
    for (int k = 0; k < KK; ++k) {
      if (k == i0) continue;
      if (i1 < 0 || w[k] > w[i1]) i1 = k;
    }
    float denom = w[i0] + w[i1] + 1e-9f;
    selE[b * 2 + 0] = i0;
    selE[b * 2 + 1] = i1;
    selW[b * 2 + 0] = w[i0] / denom;
    selW[b * 2 + 1] = w[i1] / denom;
    if (i0 != KK - 1) al[i0] = fminf(fmaxf(al[i0] - 1.f, 0.f), 1.f);
    al[KK - 1] = fmaxf(al[KK - 1], 1.f);
    for (int k = 0; k < KK; ++k) allowed[b * KK + k] = al[k];
  }
}

// y[b, h0..h0+1, :, co] = sum_{dy,dx,ci} xmod * (ws0*We[e0] + ws1*We[e1]) + bias
// xmod fused during LDS staging via rowscale. Block: 256 thr (thread = co),
// 2 output rows x 32 pixels per block.
__global__ __launch_bounds__(256) void conv_kernel(
    const float* __restrict__ xin, const float* __restrict__ rowscale,
    const float* __restrict__ We, const float* __restrict__ be,
    const int* __restrict__ selE, const float* __restrict__ selW,
    float* __restrict__ out) {
  __shared__ float xs[4 * 34 * CI_CHUNK];
  int b = blockIdx.y;
  int h0 = blockIdx.x * 2;
  int co = threadIdx.x;
  int e0 = selE[b * 2], e1 = selE[b * 2 + 1];
  float ws0 = selW[b * 2], ws1 = selW[b * 2 + 1];
  float bias = ws0 * be[e0 * CC + co] + ws1 * be[e1 * CC + co];
  float acc0[32], acc1[32];
#pragma unroll
  for (int p = 0; p < 32; ++p) { acc0[p] = bias; acc1[p] = bias; }

  for (int cic = 0; cic < CC; cic += CI_CHUNK) {
    __syncthreads();
    // stage 4 rows x 34 cols x CI_CHUNK channels, x_mod fused
    for (int idx = threadIdx.x; idx < 4 * 34 * (CI_CHUNK / 4); idx += 256) {
      int ci4 = idx & (CI_CHUNK / 4 - 1);
      int rem = idx >> 4;  // CI_CHUNK/4 == 16
      int col = rem % 34;
      int dy = rem / 34;
      int gr = h0 - 1 + dy;
      int gc = col - 1;
      float4 v = {0.f, 0.f, 0.f, 0.f};
      if (gr >= 0 && gr < 32 && gc >= 0 && gc < 32) {
        size_t base = ((((size_t)b * 32 + gr) * 32) + gc) * CC + cic + ci4 * 4;
        v = *(const float4*)(xin + base);
        float sc = rowscale[(size_t)b * SS + gr * 32 + gc];
        v.x *= sc; v.y *= sc; v.z *= sc; v.w *= sc;
      }
      *(float4*)(xs + (dy * 34 + col) * CI_CHUNK + ci4 * 4) = v;
    }
    __syncthreads();

    for (int dy = 0; dy < 3; ++dy) {
      for (int dx = 0; dx < 3; ++dx) {
        const float* w0 = We + ((((size_t)e0 * 3 + dy) * 3 + dx) * CC + cic) * CC + co;
        const float* w1 = We + ((((size_t)e1 * 3 + dy) * 3 + dx) * CC + cic) * CC + co;
        const float* xbase = xs + (dy * 34 + dx) * CI_CHUNK;
        for (int ci = 0; ci < CI_CHUNK; ++ci) {
          float w = ws0 * w0[(size_t)ci * CC] + ws1 * w1[(size_t)ci * CC];
          const float* xp = xbase + ci;
#pragma unroll
          for (int p = 0; p < 32; ++p) {
            acc0[p] += w * xp[p * CI_CHUNK];
            acc1[p] += w * xp[(p + 34) * CI_CHUNK];
          }
        }
      }
    }
  }
#pragma unroll
  for (int p = 0; p < 32; ++p) {
    out[((((size_t)b * 32 + h0) * 32) + p) * CC + co] = acc0[p];
    out[((((size_t)b * 32 + h0 + 1) * 32) + p) * CC + co] = acc1[p];
  }
}

extern "C" void kernel_launch(void* const* d_in, const int* in_sizes, int n_in,
                              void* d_out, int out_size, void* d_ws, size_t ws_size,
                              hipStream_t stream) {
  const float* x_in  = (const float*)d_in[0];
  const float* q     = (const float*)d_in[1];
  const float* Wk    = (const float*)d_in[2];
  const float* Wv    = (const float*)d_in[3];
  const float* Wmlp  = (const float*)d_in[4];
  const float* alpha = (const float*)d_in[5];
  const float* We    = (const float*)d_in[6];
  const float* be    = (const float*)d_in[7];
  float* out = (float*)d_out;
  float* ws = (float*)d_ws;

  float* qk       = ws;               // 512
  float* attn     = qk + 512;         // 65536
  float* rowscale = attn + 65536;     // 32768
  float* xa       = rowscale + 32768; // 16384
  float* allowed  = xa + 16384;       // 128
  float* selW     = allowed + 128;    // 64
  int*   selE     = (int*)(selW + 64);// 64 ints
  float* xbuf     = selW + 128;       // 8388608

  qk_kernel<<<2, 256, 0, stream>>>(Wk, q, qk);

  const float* step_in[3] = {x_in, out, xbuf};
  float* step_out[3] = {out, xbuf, out};

  for (int t = 0; t < 3; ++t) {
    const float* xc = step_in[t];
    scores_kernel<<<8192, 256, 0, stream>>>(xc, qk, attn);
    softmax_kernel<<<64, 256, 0, stream>>>(attn);
    rowscale_kernel<<<128, 256, 0, stream>>>(attn, alpha, rowscale);
    xa_kernel<<<32, 256, 0, stream>>>(xc, attn, xa);
    route_kernel<<<32, 128, 0, stream>>>(xa, Wv, Wmlp, allowed, selE, selW, t);
    conv_kernel<<<dim3(16, 32), 256, 0, stream>>>(xc, rowscale, We, be, selE, selW, step_out[t]);
  }
}

// Round 2
// 589.182 us; speedup vs baseline: 6.1623x; 6.1623x over previous
//
#include <hip/hip_runtime.h>

typedef __attribute__((ext_vector_type(8))) short bf16x8;
typedef __attribute__((ext_vector_type(4))) float f32x4;

#define CC 256
#define SS 1024
#define KK 4
#define XR 10
#define XC 34
#define KP 40

__device__ __forceinline__ unsigned int f2bf(float v) {
  unsigned int u = __float_as_uint(v);
  return (u + 0x7FFFu + ((u >> 16) & 1u)) >> 16;
}

// qk[c][n] = sum_d Wk[c, n*64+d] * q[n, d]
__global__ void qk_kernel(const float* __restrict__ Wk, const float* __restrict__ q,
                          float* __restrict__ qk) {
  int t = blockIdx.x * blockDim.x + threadIdx.x;
  if (t >= CC * 2) return;
  int c = t >> 1, n = t & 1;
  float s = 0.f;
  for (int d = 0; d < 64; ++d) s += Wk[c * 128 + n * 64 + d] * q[n * 64 + d];
  qk[c * 2 + n] = s;
}

// scores[b][n][s] = (x[b,s,:] . qk[:,n]) / 8   (one wave per pixel)
__global__ void scores_kernel(const float* __restrict__ x, const float* __restrict__ qk,
                              float* __restrict__ attn) {
  int wave = threadIdx.x >> 6, lane = threadIdx.x & 63;
  int pix = blockIdx.x * 4 + wave;
  int b = pix >> 10, s = pix & 1023;
  const float4 xv = *(const float4*)(x + (size_t)pix * CC + lane * 4);
  float d0 = 0.f, d1 = 0.f;
  const float* xp = (const float*)&xv;
#pragma unroll
  for (int j = 0; j < 4; ++j) {
    float xc = xp[j];
    d0 += xc * qk[(lane * 4 + j) * 2 + 0];
    d1 += xc * qk[(lane * 4 + j) * 2 + 1];
  }
#pragma unroll
  for (int m = 32; m >= 1; m >>= 1) {
    d0 += __shfl_xor(d0, m, 64);
    d1 += __shfl_xor(d1, m, 64);
  }
  if (lane == 0) {
    attn[((size_t)b * 2 + 0) * SS + s] = d0 * 0.125f;
    attn[((size_t)b * 2 + 1) * SS + s] = d1 * 0.125f;
  }
}

// block per batch: softmax both heads in-place + rowscale
__global__ void softmax_rs_kernel(float* __restrict__ attn, const float* __restrict__ alpha,
                                  float* __restrict__ rowscale) {
  __shared__ float red0[4], red1[4];
  int b = blockIdx.x, tid = threadIdx.x;
  float* p0 = attn + (size_t)b * 2048;
  float* p1 = p0 + 1024;
  float4 v0 = *(float4*)(p0 + tid * 4);
  float4 v1 = *(float4*)(p1 + tid * 4);
  float m0 = fmaxf(fmaxf(v0.x, v0.y), fmaxf(v0.z, v0.w));
  float m1 = fmaxf(fmaxf(v1.x, v1.y), fmaxf(v1.z, v1.w));
#pragma unroll
  for (int sh = 32; sh >= 1; sh >>= 1) {
    m0 = fmaxf(m0, __shfl_xor(m0, sh, 64));
    m1 = fmaxf(m1, __shfl_xor(m1, sh, 64));
  }
  if ((tid & 63) == 0) { red0[tid >> 6] = m0; red1[tid >> 6] = m1; }
  __syncthreads();
  m0 = fmaxf(fmaxf(red0[0], red0[1]), fmaxf(red0[2], red0[3]));
  m1 = fmaxf(fmaxf(red1[0], red1[1]), fmaxf(red1[2], red1[3]));
  float4 e0, e1;
  e0.x = expf(v0.x - m0); e0.y = expf(v0.y - m0); e0.z = expf(v0.z - m0); e0.w = expf(v0.w - m0);
  e1.x = expf(v1.x - m1); e1.y = expf(v1.y - m1); e1.z = expf(v1.z - m1); e1.w = expf(v1.w - m1);
  float s0 = e0.x + e0.y + e0.z + e0.w;
  float s1 = e1.x + e1.y + e1.z + e1.w;
#pragma unroll
  for (int sh = 32; sh >= 1; sh >>= 1) {
    s0 += __shfl_xor(s0, sh, 64);
    s1 += __shfl_xor(s1, sh, 64);
  }
  __syncthreads();
  if ((tid & 63) == 0) { red0[tid >> 6] = s0; red1[tid >> 6] = s1; }
  __syncthreads();
  s0 = red0[0] + red0[1] + red0[2] + red0[3];
  s1 = red1[0] + red1[1] + red1[2] + red1[3];
  float i0 = 1.f / s0, i1 = 1.f / s1;
  e0.x *= i0; e0.y *= i0; e0.z *= i0; e0.w *= i0;
  e1.x *= i1; e1.y *= i1; e1.z *= i1; e1.w *= i1;
  *(float4*)(p0 + tid * 4) = e0;
  *(float4*)(p1 + tid * 4) = e1;
  float al = alpha[0];
  float a = (al > 20.f) ? al : log1pf(expf(al));
  float k = 0.5f * 1024.f * a;
  float4 rs;
  rs.x = 1.f + (e0.x + e1.x) * k;
  rs.y = 1.f + (e0.y + e1.y) * k;
  rs.z = 1.f + (e0.z + e1.z) * k;
  rs.w = 1.f + (e0.w + e1.w) * k;
  *(float4*)(rowscale + (size_t)b * 1024 + tid * 4) = rs;
}

// partial xa over 64-s chunks: xa_part[b][ch][n][c]
__global__ void xa_part_kernel(const float* __restrict__ x, const float* __restrict__ attn,
                               float* __restrict__ xa_part) {
  int ch = blockIdx.x, b = blockIdx.y, c = threadIdx.x;
  int s0 = ch * 64;
  const float* a0 = attn + (size_t)b * 2048 + s0;
  const float* a1 = a0 + 1024;
  const float* xb = x + ((size_t)b * 1024 + s0) * CC + c;
  float acc0 = 0.f, acc1 = 0.f;
  for (int i = 0; i < 64; ++i) {
    float xv = xb[(size_t)i * CC];
    acc0 += a0[i] * xv;
    acc1 += a1[i] * xv;
  }
  float* o = xa_part + ((size_t)b * 16 + ch) * 512;
  o[c] = acc0;
  o[256 + c] = acc1;
}

// reduce xa_part -> pooled -> logits -> top-2 routing
__global__ void route_kernel(const float* __restrict__ xa_part, const float* __restrict__ Wv,
                             const float* __restrict__ Wmlp, float* __restrict__ allowed,
                             int* __restrict__ selE, float* __restrict__ selW, int step) {
  __shared__ float xs[512];
  __shared__ float pooled[128];
  __shared__ float lg[4];
  int b = blockIdx.x, tid = threadIdx.x;
#pragma unroll
  for (int i = 0; i < 2; ++i) {
    int id = tid + i * 256;
    float s = 0.f;
    for (int ch = 0; ch < 16; ++ch) s += xa_part[((size_t)b * 16 + ch) * 512 + id];
    xs[id] = s;
  }
  __syncthreads();
  if (tid < 128) {
    int n = tid >> 6;
    float s = 0.f;
    const float* xr = xs + n * 256;
    for (int c = 0; c < 256; ++c) s += xr[c] * Wv[(size_t)c * 128 + tid];
    pooled[tid] = s;
  }
  __syncthreads();
  if (tid < 4) {
    float s = 0.f;
    for (int d = 0; d < 128; ++d) s += pooled[d] * Wmlp[d * 4 + tid];
    lg[tid] = s;
  }
  __syncthreads();
  if (tid == 0) {
    float al[KK];
    if (step == 0) { for (int k = 0; k < KK; ++k) al[k] = 1.f; }
    else           { for (int k = 0; k < KK; ++k) al[k] = allowed[b * KK + k]; }
    float ml[KK];
    for (int k = 0; k < KK; ++k)
      ml[k] = (al[k] > 0.5f) ? lg[k] * (1.f / 1.5f) : (-1e9f) * (1.f / 1.5f);
    float m = ml[0];
    for (int k = 1; k < KK; ++k) m = fmaxf(m, ml[k]);
    float e[KK], ssum = 0.f;
    for (int k = 0; k < KK; ++k) { e[k] = expf(ml[k] - m); ssum += e[k]; }
    float w[KK];
    for (int k = 0; k < KK; ++k) w[k] = e[k] / ssum;
    int i0 = 0;
    for (int k = 1; k < KK; ++k) if (w[k] > w[i0]) i0 = k;
    int i1 = -1;
    for (int k = 0; k < KK; ++k) {
      if (k == i0) continue;
      if (i1 < 0 || w[k] > w[i1]) i1 = k;
    }
    float denom = w[i0] + w[i1] + 1e-9f;
    selE[b * 2 + 0] = i0;
    selE[b * 2 + 1] = i1;
    selW[b * 2 + 0] = w[i0] / denom;
    selW[b * 2 + 1] = w[i1] / denom;
    if (i0 != KK - 1) al[i0] = fminf(fmaxf(al[i0] - 1.f, 0.f), 1.f);
    al[KK - 1] = fmaxf(al[KK - 1], 1.f);
    for (int k = 0; k < KK; ++k) allowed[b * KK + k] = al[k];
  }
}

// split all expert weights to bf16 hi/lo in transposed layout:
// Wt[(e*2+h)*72 + tap*8 + kc][co(256)][ki(32)]
__global__ void prep_w_kernel(const float* __restrict__ We, unsigned short* __restrict__ Wt) {
  int bid = blockIdx.x;  // 288 = 4*9*8
  int e = bid / 72, rem = bid % 72, tap = rem / 8, kc = rem % 8;
  int co = threadIdx.x;
  __shared__ float tile[32][257];
  const float* src = We + (size_t)(e * 9 + tap) * 65536 + (size_t)(kc * 32) * 256 + co;
  for (int ci = 0; ci < 32; ++ci) tile[ci][co] = src[(size_t)ci * 256];
  __syncthreads();
  __align__(16) unsigned short hh[32];
  __align__(16) unsigned short ll[32];
#pragma unroll
  for (int ki = 0; ki < 32; ++ki) {
    float v = tile[ki][co];
    unsigned int h = f2bf(v);
    float fh = __uint_as_float(h << 16);
    unsigned int l = f2bf(v - fh);
    hh[ki] = (unsigned short)h;
    ll[ki] = (unsigned short)l;
  }
  size_t bh = (size_t)((e * 2 + 0) * 72 + tap * 8 + kc) * 8192 + (size_t)co * 32;
  size_t bl = (size_t)((e * 2 + 1) * 72 + tap * 8 + kc) * 8192 + (size_t)co * 32;
#pragma unroll
  for (int j = 0; j < 4; ++j) {
    *(uint4*)(Wt + bh + j * 8) = *(const uint4*)(hh + j * 8);
    *(uint4*)(Wt + bl + j * 8) = *(const uint4*)(ll + j * 8);
  }
}

// MFMA implicit-GEMM conv: block = 512 thr, M=256 pixels (8 rows), N=128 cos,
// 2 experts x 3 split-bf16 terms accumulated in f32.
__global__ __launch_bounds__(512, 2) void conv_kernel(
    const float* __restrict__ xin, const float* __restrict__ rowscale,
    const unsigned short* __restrict__ Wt, const float* __restrict__ be,
    const int* __restrict__ selE, const float* __restrict__ selW,
    float* __restrict__ out) {
  __shared__ unsigned short xs_h[XR * XC * KP];
  __shared__ unsigned short xs_l[XR * XC * KP];
  __shared__ unsigned short Bl[4 * 128 * KP];
  __shared__ float rs_lds[XR * XC];

  int b = blockIdx.y;
  int mt = blockIdx.x >> 1, nt = blockIdx.x & 1;
  int h0 = mt * 8;
  int tid = threadIdx.x;
  int lane = tid & 63, wid = tid >> 6;
  int wm = wid >> 1, wn = wid & 1;
  int l15 = lane & 15, kl = lane >> 4;

  int e0 = selE[b * 2], e1 = selE[b * 2 + 1];
  float w0 = selW[b * 2], w1 = selW[b * 2 + 1];

  if (tid < XR * XC) {
    int r = tid / XC, c = tid - r * XC;
    int gr = h0 - 1 + r, gc = c - 1;
    float v = 0.f;
    if (gr >= 0 && gr < 32 && gc >= 0 && gc < 32)
      v = rowscale[(size_t)b * 1024 + gr * 32 + gc];
    rs_lds[tid] = v;
  }

  int prow[4], pcb[4];
#pragma unroll
  for (int mf = 0; mf < 4; ++mf) {
    int pm = wm * 64 + mf * 16;
    prow[mf] = pm >> 5;
    pcb[mf] = pm & 31;
  }
  int bidx[4];
#pragma unroll
  for (int nf = 0; nf < 4; ++nf) bidx[nf] = (wn * 64 + nf * 16 + l15) * KP + kl * 8;

  int con = nt * 128 + wn * 64 + l15;
  float bias[4];
#pragma unroll
  for (int nf = 0; nf < 4; ++nf)
    bias[nf] = w0 * be[e0 * 256 + con + nf * 16] + w1 * be[e1 * 256 + con + nf * 16];

  f32x4 acc[2][4][4];
#pragma unroll
  for (int e = 0; e < 2; ++e)
#pragma unroll
    for (int mf = 0; mf < 4; ++mf)
#pragma unroll
      for (int nf = 0; nf < 4; ++nf) acc[e][mf][nf] = (f32x4){0.f, 0.f, 0.f, 0.f};

  auto stage_x = [&](int kc) {
    for (int idx = tid; idx < XR * XC * 8; idx += 512) {
      int ki4 = idx & 7, cell = idx >> 3;
      int r = cell / XC, c = cell - r * XC;
      int gr = h0 - 1 + r, gc = c - 1;
      float4 v = make_float4(0.f, 0.f, 0.f, 0.f);
      if (gr >= 0 && gr < 32 && gc >= 0 && gc < 32)
        v = *(const float4*)(xin + (((size_t)b * 32 + gr) * 32 + gc) * 256 + kc * 32 + ki4 * 4);
      float sc = rs_lds[cell];
      float x0 = v.x * sc, x1 = v.y * sc, x2 = v.z * sc, x3 = v.w * sc;
      unsigned int h0b = f2bf(x0), h1b = f2bf(x1), h2b = f2bf(x2), h3b = f2bf(x3);
      unsigned int l0b = f2bf(x0 - __uint_as_float(h0b << 16));
      unsigned int l1b = f2bf(x1 - __uint_as_float(h1b << 16));
      unsigned int l2b = f2bf(x2 - __uint_as_float(h2b << 16));
      unsigned int l3b = f2bf(x3 - __uint_as_float(h3b << 16));
      uint2 hw = make_uint2(h0b | (h1b << 16), h2b | (h3b << 16));
      uint2 lw = make_uint2(l0b | (l1b << 16), l2b | (l3b << 16));
      *(uint2*)(xs_h + cell * KP + ki4 * 4) = hw;
      *(uint2*)(xs_l + cell * KP + ki4 * 4) = lw;
    }
  };

  auto b_src = [&](int tap, int kc, int a) -> const uint4* {
    int se = (a < 2) ? e0 : e1;
    int h = a & 1;
    size_t base = (size_t)((se * 2 + h) * 72 + tap * 8 + kc) * 8192 + (size_t)nt * 4096;
    return (const uint4*)(Wt + base) + tid;
  };

  __syncthreads();  // rs_lds ready
  stage_x(0);
  {
    uint4 p0 = *b_src(0, 0, 0), p1 = *b_src(0, 0, 1), p2 = *b_src(0, 0, 2), p3 = *b_src(0, 0, 3);
    int lw = (tid >> 2) * KP + (tid & 3) * 8;
    *(uint4*)(Bl + 0 * 5120 + lw) = p0;
    *(uint4*)(Bl + 1 * 5120 + lw) = p1;
    *(uint4*)(Bl + 2 * 5120 + lw) = p2;
    *(uint4*)(Bl + 3 * 5120 + lw) = p3;
  }
  __syncthreads();

  int tap = 0, kc = 0;
  for (int tk = 0; tk < 72; ++tk) {
    int ntap = tap + 1, nkc = kc;
    if (ntap == 9) { ntap = 0; nkc = kc + 1; }
    bool pf = (tk < 71);
    uint4 p0, p1, p2, p3;
    if (pf) {
      p0 = *b_src(ntap, nkc, 0);
      p1 = *b_src(ntap, nkc, 1);
      p2 = *b_src(ntap, nkc, 2);
      p3 = *b_src(ntap, nkc, 3);
    }

    int dy = tap / 3;
    int dx = tap - dy * 3;
    bf16x8 af[2][4];
#pragma unroll
    for (int mf = 0; mf < 4; ++mf) {
      int aidx = ((prow[mf] + dy) * XC + pcb[mf] + l15 + dx) * KP + kl * 8;
      af[0][mf] = *(const bf16x8*)(xs_h + aidx);
      af[1][mf] = *(const bf16x8*)(xs_l + aidx);
    }
#pragma unroll
    for (int e = 0; e < 2; ++e) {
#pragma unroll
      for (int t3 = 0; t3 < 3; ++t3) {
        const int ha = (t3 == 2) ? 1 : 0;
        const int hb = (t3 == 1) ? 1 : 0;
        const unsigned short* bp = Bl + (e * 2 + hb) * 5120;
        bf16x8 bf[4];
#pragma unroll
        for (int nf = 0; nf < 4; ++nf) bf[nf] = *(const bf16x8*)(bp + bidx[nf]);
#pragma unroll
        for (int mf = 0; mf < 4; ++mf)
#pragma unroll
          for (int nf = 0; nf < 4; ++nf)
            acc[e][mf][nf] = __builtin_amdgcn_mfma_f32_16x16x32_bf16(
                af[ha][mf], bf[nf], acc[e][mf][nf], 0, 0, 0);
      }
    }
    __syncthreads();
    if (pf && ntap == 0) stage_x(nkc);
    if (pf) {
      int lw = (tid >> 2) * KP + (tid & 3) * 8;
      *(uint4*)(Bl + 0 * 5120 + lw) = p0;
      *(uint4*)(Bl + 1 * 5120 + lw) = p1;
      *(uint4*)(Bl + 2 * 5120 + lw) = p2;
      *(uint4*)(Bl + 3 * 5120 + lw) = p3;
    }
    __syncthreads();
    tap = ntap;
    kc = nkc;
  }

#pragma unroll
  for (int mf = 0; mf < 4; ++mf) {
    size_t rowbase = ((size_t)b * 32 + h0 + prow[mf]) * 32;
#pragma unroll
    for (int nf = 0; nf < 4; ++nf) {
      int co = nt * 128 + wn * 64 + nf * 16 + l15;
#pragma unroll
      for (int r = 0; r < 4; ++r) {
        int col = pcb[mf] + kl * 4 + r;
        out[(rowbase + col) * 256 + co] =
            w0 * acc[0][mf][nf][r] + w1 * acc[1][mf][nf][r] + bias[nf];
      }
    }
  }
}

extern "C" void kernel_launch(void* const* d_in, const int* in_sizes, int n_in,
                              void* d_out, int out_size, void* d_ws, size_t ws_size,
                              hipStream_t stream) {
  const float* x_in  = (const float*)d_in[0];
  const float* q     = (const float*)d_in[1];
  const float* Wk    = (const float*)d_in[2];
  const float* Wv    = (const float*)d_in[3];
  const float* Wmlp  = (const float*)d_in[4];
  const float* alpha = (const float*)d_in[5];
  const float* We    = (const float*)d_in[6];
  const float* be    = (const float*)d_in[7];
  float* out = (float*)d_out;
  float* ws = (float*)d_ws;

  float* qk       = ws;                 // 512
  float* attn     = qk + 512;           // 65536
  float* rowscale = attn + 65536;       // 32768
  float* xa_part  = rowscale + 32768;   // 262144
  float* allowed  = xa_part + 262144;   // 128
  float* selW     = allowed + 128;      // 64
  int*   selE     = (int*)(selW + 64);  // 64
  float* xbuf     = selW + 128;         // 8388608
  unsigned short* Wt = (unsigned short*)(xbuf + 8388608);  // 4718592 ushorts

  prep_w_kernel<<<288, 256, 0, stream>>>(We, Wt);
  qk_kernel<<<2, 256, 0, stream>>>(Wk, q, qk);

  const float* step_in[3] = {x_in, out, xbuf};
  float* step_out[3] = {out, xbuf, out};

  for (int t = 0; t < 3; ++t) {
    const float* xc = step_in[t];
    scores_kernel<<<8192, 256, 0, stream>>>(xc, qk, attn);
    softmax_rs_kernel<<<32, 256, 0, stream>>>(attn, alpha, rowscale);
    xa_part_kernel<<<dim3(16, 32), 256, 0, stream>>>(xc, attn, xa_part);
    route_kernel<<<32, 256, 0, stream>>>(xa_part, Wv, Wmlp, allowed, selE, selW, t);
    conv_kernel<<<dim3(8, 32), 512, 0, stream>>>(xc, rowscale, Wt, be, selE, selW, step_out[t]);
  }
}

// Round 3
// 586.027 us; speedup vs baseline: 6.1955x; 1.0054x over previous
//
#include <hip/hip_runtime.h>

typedef __attribute__((ext_vector_type(8))) short bf16x8;
typedef __attribute__((ext_vector_type(4))) float f32x4;

#define CC 256
#define SS 1024
#define KK 4
#define XR 6
#define XC 34
#define KP 40

__device__ __forceinline__ unsigned int f2bf(float v) {
  unsigned int u = __float_as_uint(v);
  return (u + 0x7FFFu + ((u >> 16) & 1u)) >> 16;
}

// qk[c][n] = sum_d Wk[c, n*64+d] * q[n, d]
__global__ void qk_kernel(const float* __restrict__ Wk, const float* __restrict__ q,
                          float* __restrict__ qk) {
  int t = blockIdx.x * blockDim.x + threadIdx.x;
  if (t >= CC * 2) return;
  int c = t >> 1, n = t & 1;
  float s = 0.f;
  for (int d = 0; d < 64; ++d) s += Wk[c * 128 + n * 64 + d] * q[n * 64 + d];
  qk[c * 2 + n] = s;
}

// scores[b][n][s] = (x[b,s,:] . qk[:,n]) / 8   (one wave per pixel)
__global__ void scores_kernel(const float* __restrict__ x, const float* __restrict__ qk,
                              float* __restrict__ attn) {
  int wave = threadIdx.x >> 6, lane = threadIdx.x & 63;
  int pix = blockIdx.x * 4 + wave;
  int b = pix >> 10, s = pix & 1023;
  const float4 xv = *(const float4*)(x + (size_t)pix * CC + lane * 4);
  float d0 = 0.f, d1 = 0.f;
  const float* xp = (const float*)&xv;
#pragma unroll
  for (int j = 0; j < 4; ++j) {
    float xc = xp[j];
    d0 += xc * qk[(lane * 4 + j) * 2 + 0];
    d1 += xc * qk[(lane * 4 + j) * 2 + 1];
  }
#pragma unroll
  for (int m = 32; m >= 1; m >>= 1) {
    d0 += __shfl_xor(d0, m, 64);
    d1 += __shfl_xor(d1, m, 64);
  }
  if (lane == 0) {
    attn[((size_t)b * 2 + 0) * SS + s] = d0 * 0.125f;
    attn[((size_t)b * 2 + 1) * SS + s] = d1 * 0.125f;
  }
}

// block per batch: softmax both heads in-place + rowscale
__global__ void softmax_rs_kernel(float* __restrict__ attn, const float* __restrict__ alpha,
                                  float* __restrict__ rowscale) {
  __shared__ float red0[4], red1[4];
  int b = blockIdx.x, tid = threadIdx.x;
  float* p0 = attn + (size_t)b * 2048;
  float* p1 = p0 + 1024;
  float4 v0 = *(float4*)(p0 + tid * 4);
  float4 v1 = *(float4*)(p1 + tid * 4);
  float m0 = fmaxf(fmaxf(v0.x, v0.y), fmaxf(v0.z, v0.w));
  float m1 = fmaxf(fmaxf(v1.x, v1.y), fmaxf(v1.z, v1.w));
#pragma unroll
  for (int sh = 32; sh >= 1; sh >>= 1) {
    m0 = fmaxf(m0, __shfl_xor(m0, sh, 64));
    m1 = fmaxf(m1, __shfl_xor(m1, sh, 64));
  }
  if ((tid & 63) == 0) { red0[tid >> 6] = m0; red1[tid >> 6] = m1; }
  __syncthreads();
  m0 = fmaxf(fmaxf(red0[0], red0[1]), fmaxf(red0[2], red0[3]));
  m1 = fmaxf(fmaxf(red1[0], red1[1]), fmaxf(red1[2], red1[3]));
  float4 e0, e1;
  e0.x = expf(v0.x - m0); e0.y = expf(v0.y - m0); e0.z = expf(v0.z - m0); e0.w = expf(v0.w - m0);
  e1.x = expf(v1.x - m1); e1.y = expf(v1.y - m1); e1.z = expf(v1.z - m1); e1.w = expf(v1.w - m1);
  float s0 = e0.x + e0.y + e0.z + e0.w;
  float s1 = e1.x + e1.y + e1.z + e1.w;
#pragma unroll
  for (int sh = 32; sh >= 1; sh >>= 1) {
    s0 += __shfl_xor(s0, sh, 64);
    s1 += __shfl_xor(s1, sh, 64);
  }
  __syncthreads();
  if ((tid & 63) == 0) { red0[tid >> 6] = s0; red1[tid >> 6] = s1; }
  __syncthreads();
  s0 = red0[0] + red0[1] + red0[2] + red0[3];
  s1 = red1[0] + red1[1] + red1[2] + red1[3];
  float i0 = 1.f / s0, i1 = 1.f / s1;
  e0.x *= i0; e0.y *= i0; e0.z *= i0; e0.w *= i0;
  e1.x *= i1; e1.y *= i1; e1.z *= i1; e1.w *= i1;
  *(float4*)(p0 + tid * 4) = e0;
  *(float4*)(p1 + tid * 4) = e1;
  float al = alpha[0];
  float a = (al > 20.f) ? al : log1pf(expf(al));
  float k = 0.5f * 1024.f * a;
  float4 rs;
  rs.x = 1.f + (e0.x + e1.x) * k;
  rs.y = 1.f + (e0.y + e1.y) * k;
  rs.z = 1.f + (e0.z + e1.z) * k;
  rs.w = 1.f + (e0.w + e1.w) * k;
  *(float4*)(rowscale + (size_t)b * 1024 + tid * 4) = rs;
}

// partial xa over 64-s chunks: xa_part[b][ch][n][c]
__global__ void xa_part_kernel(const float* __restrict__ x, const float* __restrict__ attn,
                               float* __restrict__ xa_part) {
  int ch = blockIdx.x, b = blockIdx.y, c = threadIdx.x;
  int s0 = ch * 64;
  const float* a0 = attn + (size_t)b * 2048 + s0;
  const float* a1 = a0 + 1024;
  const float* xb = x + ((size_t)b * 1024 + s0) * CC + c;
  float acc0 = 0.f, acc1 = 0.f;
  for (int i = 0; i < 64; ++i) {
    float xv = xb[(size_t)i * CC];
    acc0 += a0[i] * xv;
    acc1 += a1[i] * xv;
  }
  float* o = xa_part + ((size_t)b * 16 + ch) * 512;
  o[c] = acc0;
  o[256 + c] = acc1;
}

// reduce xa_part -> pooled -> logits -> top-2 routing
__global__ void route_kernel(const float* __restrict__ xa_part, const float* __restrict__ Wv,
                             const float* __restrict__ Wmlp, float* __restrict__ allowed,
                             int* __restrict__ selE, float* __restrict__ selW, int step) {
  __shared__ float xs[512];
  __shared__ float pooled[128];
  __shared__ float lg[4];
  int b = blockIdx.x, tid = threadIdx.x;
#pragma unroll
  for (int i = 0; i < 2; ++i) {
    int id = tid + i * 256;
    float s = 0.f;
    for (int ch = 0; ch < 16; ++ch) s += xa_part[((size_t)b * 16 + ch) * 512 + id];
    xs[id] = s;
  }
  __syncthreads();
  if (tid < 128) {
    int n = tid >> 6;
    float s = 0.f;
    const float* xr = xs + n * 256;
    for (int c = 0; c < 256; ++c) s += xr[c] * Wv[(size_t)c * 128 + tid];
    pooled[tid] = s;
  }
  __syncthreads();
  if (tid < 4) {
    float s = 0.f;
    for (int d = 0; d < 128; ++d) s += pooled[d] * Wmlp[d * 4 + tid];
    lg[tid] = s;
  }
  __syncthreads();
  if (tid == 0) {
    float al[KK];
    if (step == 0) { for (int k = 0; k < KK; ++k) al[k] = 1.f; }
    else           { for (int k = 0; k < KK; ++k) al[k] = allowed[b * KK + k]; }
    float ml[KK];
    for (int k = 0; k < KK; ++k)
      ml[k] = (al[k] > 0.5f) ? lg[k] * (1.f / 1.5f) : (-1e9f) * (1.f / 1.5f);
    float m = ml[0];
    for (int k = 1; k < KK; ++k) m = fmaxf(m, ml[k]);
    float e[KK], ssum = 0.f;
    for (int k = 0; k < KK; ++k) { e[k] = expf(ml[k] - m); ssum += e[k]; }
    float w[KK];
    for (int k = 0; k < KK; ++k) w[k] = e[k] / ssum;
    int i0 = 0;
    for (int k = 1; k < KK; ++k) if (w[k] > w[i0]) i0 = k;
    int i1 = -1;
    for (int k = 0; k < KK; ++k) {
      if (k == i0) continue;
      if (i1 < 0 || w[k] > w[i1]) i1 = k;
    }
    float denom = w[i0] + w[i1] + 1e-9f;
    selE[b * 2 + 0] = i0;
    selE[b * 2 + 1] = i1;
    selW[b * 2 + 0] = w[i0] / denom;
    selW[b * 2 + 1] = w[i1] / denom;
    if (i0 != KK - 1) al[i0] = fminf(fmaxf(al[i0] - 1.f, 0.f), 1.f);
    al[KK - 1] = fmaxf(al[KK - 1], 1.f);
    for (int k = 0; k < KK; ++k) allowed[b * KK + k] = al[k];
  }
}

// split all expert weights to bf16 hi/lo in transposed layout:
// Wt[(e*2+h)*72 + tap*8 + kc][co(256)][ki(32)]
__global__ void prep_w_kernel(const float* __restrict__ We, unsigned short* __restrict__ Wt) {
  int bid = blockIdx.x;  // 288 = 4*9*8
  int e = bid / 72, rem = bid % 72, tap = rem / 8, kc = rem % 8;
  int co = threadIdx.x;
  __shared__ float tile[32][257];
  const float* src = We + (size_t)(e * 9 + tap) * 65536 + (size_t)(kc * 32) * 256 + co;
  for (int ci = 0; ci < 32; ++ci) tile[ci][co] = src[(size_t)ci * 256];
  __syncthreads();
  __align__(16) unsigned short hh[32];
  __align__(16) unsigned short ll[32];
#pragma unroll
  for (int ki = 0; ki < 32; ++ki) {
    float v = tile[ki][co];
    unsigned int h = f2bf(v);
    float fh = __uint_as_float(h << 16);
    unsigned int l = f2bf(v - fh);
    hh[ki] = (unsigned short)h;
    ll[ki] = (unsigned short)l;
  }
  size_t bh = (size_t)((e * 2 + 0) * 72 + tap * 8 + kc) * 8192 + (size_t)co * 32;
  size_t bl = (size_t)((e * 2 + 1) * 72 + tap * 8 + kc) * 8192 + (size_t)co * 32;
#pragma unroll
  for (int j = 0; j < 4; ++j) {
    *(uint4*)(Wt + bh + j * 8) = *(const uint4*)(hh + j * 8);
    *(uint4*)(Wt + bl + j * 8) = *(const uint4*)(ll + j * 8);
  }
}

// MFMA implicit-GEMM conv with per-batch expert-combined weights (in-register
// combine during B staging). Block = 512 thr (8 waves: wm 0..1 x wn 0..3),
// M=128 pixels (4 rows + halo), N=128 cos. 3 split-bf16 terms, f32 accum.
__global__ __launch_bounds__(512, 4) void conv_kernel(
    const float* __restrict__ xin, const float* __restrict__ rowscale,
    const unsigned short* __restrict__ Wt, const float* __restrict__ be,
    const int* __restrict__ selE, const float* __restrict__ selW,
    float* __restrict__ out) {
  __shared__ unsigned short xs_h[XR * XC * KP];
  __shared__ unsigned short xs_l[XR * XC * KP];
  __shared__ unsigned short Bl[2 * 128 * KP];
  __shared__ float rs_lds[XR * XC];

  int b = blockIdx.y;
  int mt = blockIdx.x >> 1, nt = blockIdx.x & 1;
  int h0 = mt * 4;
  int tid = threadIdx.x;
  int lane = tid & 63, wid = tid >> 6;
  int wm = wid >> 2, wn = wid & 3;
  int l15 = lane & 15, kl = lane >> 4;

  int e0 = selE[b * 2], e1 = selE[b * 2 + 1];
  float w0 = selW[b * 2], w1 = selW[b * 2 + 1];

  if (tid < XR * XC) {
    int r = tid / XC, c = tid - r * XC;
    int gr = h0 - 1 + r, gc = c - 1;
    float v = 0.f;
    if (gr >= 0 && gr < 32 && gc >= 0 && gc < 32)
      v = rowscale[(size_t)b * 1024 + gr * 32 + gc];
    rs_lds[tid] = v;
  }

  int prow[4], pcb[4];
#pragma unroll
  for (int mf = 0; mf < 4; ++mf) {
    int pm = wm * 64 + mf * 16;
    prow[mf] = pm >> 5;
    pcb[mf] = pm & 31;
  }
  int bidx[2];
#pragma unroll
  for (int nf = 0; nf < 2; ++nf) bidx[nf] = (wn * 32 + nf * 16 + l15) * KP + kl * 8;

  int con = nt * 128 + wn * 32 + l15;
  float bias[2];
#pragma unroll
  for (int nf = 0; nf < 2; ++nf)
    bias[nf] = w0 * be[e0 * 256 + con + nf * 16] + w1 * be[e1 * 256 + con + nf * 16];

  f32x4 acc[4][2];
#pragma unroll
  for (int mf = 0; mf < 4; ++mf)
#pragma unroll
    for (int nf = 0; nf < 2; ++nf) acc[mf][nf] = (f32x4){0.f, 0.f, 0.f, 0.f};

  auto stage_x = [&](int kc) {
    for (int idx = tid; idx < XR * XC * 8; idx += 512) {
      int ki4 = idx & 7, cell = idx >> 3;
      int r = cell / XC, c = cell - r * XC;
      int gr = h0 - 1 + r, gc = c - 1;
      float4 v = make_float4(0.f, 0.f, 0.f, 0.f);
      if (gr >= 0 && gr < 32 && gc >= 0 && gc < 32)
        v = *(const float4*)(xin + (((size_t)b * 32 + gr) * 32 + gc) * 256 + kc * 32 + ki4 * 4);
      float sc = rs_lds[cell];
      float x0 = v.x * sc, x1 = v.y * sc, x2 = v.z * sc, x3 = v.w * sc;
      unsigned int h0b = f2bf(x0), h1b = f2bf(x1), h2b = f2bf(x2), h3b = f2bf(x3);
      unsigned int l0b = f2bf(x0 - __uint_as_float(h0b << 16));
      unsigned int l1b = f2bf(x1 - __uint_as_float(h1b << 16));
      unsigned int l2b = f2bf(x2 - __uint_as_float(h2b << 16));
      unsigned int l3b = f2bf(x3 - __uint_as_float(h3b << 16));
      uint2 hw = make_uint2(h0b | (h1b << 16), h2b | (h3b << 16));
      uint2 lw = make_uint2(l0b | (l1b << 16), l2b | (l3b << 16));
      *(uint2*)(xs_h + cell * KP + ki4 * 4) = hw;
      *(uint2*)(xs_l + cell * KP + ki4 * 4) = lw;
    }
  };

  auto b_src = [&](int tap, int kc, int a) -> const uint4* {
    int se = (a < 2) ? e0 : e1;
    int h = a & 1;
    size_t base = (size_t)((se * 2 + h) * 72 + tap * 8 + kc) * 8192 + (size_t)nt * 4096;
    return (const uint4*)(Wt + base) + tid;
  };

  // combine prefetched expert weights -> (hi, lo) bf16, write to Bl
  auto combine_write = [&](uint4 ph0, uint4 pl0, uint4 ph1, uint4 pl1) {
    int lw = (tid >> 2) * KP + (tid & 3) * 8;
    const unsigned short* H0 = (const unsigned short*)&ph0;
    const unsigned short* L0 = (const unsigned short*)&pl0;
    const unsigned short* H1 = (const unsigned short*)&ph1;
    const unsigned short* L1 = (const unsigned short*)&pl1;
    unsigned int hh[4], ll[4];
#pragma unroll
    for (int j = 0; j < 4; ++j) {
      unsigned int hp = 0, lp = 0;
#pragma unroll
      for (int s = 0; s < 2; ++s) {
        int e = j * 2 + s;
        float f0 = __uint_as_float((unsigned int)H0[e] << 16) +
                   __uint_as_float((unsigned int)L0[e] << 16);
        float f1 = __uint_as_float((unsigned int)H1[e] << 16) +
                   __uint_as_float((unsigned int)L1[e] << 16);
        float c = w0 * f0 + w1 * f1;
        unsigned int hb = f2bf(c);
        unsigned int lb = f2bf(c - __uint_as_float(hb << 16));
        hp |= hb << (16 * s);
        lp |= lb << (16 * s);
      }
      hh[j] = hp;
      ll[j] = lp;
    }
    *(uint4*)(Bl + lw) = make_uint4(hh[0], hh[1], hh[2], hh[3]);
    *(uint4*)(Bl + 5120 + lw) = make_uint4(ll[0], ll[1], ll[2], ll[3]);
  };

  __syncthreads();  // rs_lds ready
  stage_x(0);
  {
    uint4 p0 = *b_src(0, 0, 0), p1 = *b_src(0, 0, 1), p2 = *b_src(0, 0, 2), p3 = *b_src(0, 0, 3);
    combine_write(p0, p1, p2, p3);
  }
  __syncthreads();

  int tap = 0, kc = 0;
  for (int tk = 0; tk < 72; ++tk) {
    int ntap = tap + 1, nkc = kc;
    if (ntap == 9) { ntap = 0; nkc = kc + 1; }
    bool pf = (tk < 71);
    uint4 p0, p1, p2, p3;
    if (pf) {
      p0 = *b_src(ntap, nkc, 0);
      p1 = *b_src(ntap, nkc, 1);
      p2 = *b_src(ntap, nkc, 2);
      p3 = *b_src(ntap, nkc, 3);
    }

    int dy = tap / 3;
    int dx = tap - dy * 3;
    int aoff[4];
#pragma unroll
    for (int mf = 0; mf < 4; ++mf)
      aoff[mf] = ((prow[mf] + dy) * XC + pcb[mf] + l15 + dx) * KP + kl * 8;

    bf16x8 afh[4], bf0[2], bf1[2];
#pragma unroll
    for (int mf = 0; mf < 4; ++mf) afh[mf] = *(const bf16x8*)(xs_h + aoff[mf]);
#pragma unroll
    for (int nf = 0; nf < 2; ++nf) {
      bf0[nf] = *(const bf16x8*)(Bl + bidx[nf]);
      bf1[nf] = *(const bf16x8*)(Bl + 5120 + bidx[nf]);
    }
#pragma unroll
    for (int mf = 0; mf < 4; ++mf)
#pragma unroll
      for (int nf = 0; nf < 2; ++nf)
        acc[mf][nf] = __builtin_amdgcn_mfma_f32_16x16x32_bf16(afh[mf], bf0[nf], acc[mf][nf], 0, 0, 0);
#pragma unroll
    for (int mf = 0; mf < 4; ++mf)
#pragma unroll
      for (int nf = 0; nf < 2; ++nf)
        acc[mf][nf] = __builtin_amdgcn_mfma_f32_16x16x32_bf16(afh[mf], bf1[nf], acc[mf][nf], 0, 0, 0);
    bf16x8 afl[4];
#pragma unroll
    for (int mf = 0; mf < 4; ++mf) afl[mf] = *(const bf16x8*)(xs_l + aoff[mf]);
#pragma unroll
    for (int mf = 0; mf < 4; ++mf)
#pragma unroll
      for (int nf = 0; nf < 2; ++nf)
        acc[mf][nf] = __builtin_amdgcn_mfma_f32_16x16x32_bf16(afl[mf], bf0[nf], acc[mf][nf], 0, 0, 0);

    __syncthreads();
    if (pf && ntap == 0) stage_x(nkc);
    if (pf) combine_write(p0, p1, p2, p3);
    __syncthreads();
    tap = ntap;
    kc = nkc;
  }

#pragma unroll
  for (int mf = 0; mf < 4; ++mf) {
    size_t rowbase = ((size_t)b * 32 + h0 + prow[mf]) * 32;
#pragma unroll
    for (int nf = 0; nf < 2; ++nf) {
      int co = nt * 128 + wn * 32 + nf * 16 + l15;
#pragma unroll
      for (int r = 0; r < 4; ++r) {
        int col = pcb[mf] + kl * 4 + r;
        out[(rowbase + col) * 256 + co] = acc[mf][nf][r] + bias[nf];
      }
    }
  }
}

extern "C" void kernel_launch(void* const* d_in, const int* in_sizes, int n_in,
                              void* d_out, int out_size, void* d_ws, size_t ws_size,
                              hipStream_t stream) {
  const float* x_in  = (const float*)d_in[0];
  const float* q     = (const float*)d_in[1];
  const float* Wk    = (const float*)d_in[2];
  const float* Wv    = (const float*)d_in[3];
  const float* Wmlp  = (const float*)d_in[4];
  const float* alpha = (const float*)d_in[5];
  const float* We    = (const float*)d_in[6];
  const float* be    = (const float*)d_in[7];
  float* out = (float*)d_out;
  float* ws = (float*)d_ws;

  float* qk       = ws;                 // 512
  float* attn     = qk + 512;           // 65536
  float* rowscale = attn + 65536;       // 32768
  float* xa_part  = rowscale + 32768;   // 262144
  float* allowed  = xa_part + 262144;   // 128
  float* selW     = allowed + 128;      // 64
  int*   selE     = (int*)(selW + 64);  // 64
  float* xbuf     = selW + 128;         // 8388608
  unsigned short* Wt = (unsigned short*)(xbuf + 8388608);  // 4718592 ushorts

  prep_w_kernel<<<288, 256, 0, stream>>>(We, Wt);
  qk_kernel<<<2, 256, 0, stream>>>(Wk, q, qk);

  const float* step_in[3] = {x_in, out, xbuf};
  float* step_out[3] = {out, xbuf, out};

  for (int t = 0; t < 3; ++t) {
    const float* xc = step_in[t];
    scores_kernel<<<8192, 256, 0, stream>>>(xc, qk, attn);
    softmax_rs_kernel<<<32, 256, 0, stream>>>(attn, alpha, rowscale);
    xa_part_kernel<<<dim3(16, 32), 256, 0, stream>>>(xc, attn, xa_part);
    route_kernel<<<32, 256, 0, stream>>>(xa_part, Wv, Wmlp, allowed, selE, selW, t);
    conv_kernel<<<dim3(16, 32), 512, 0, stream>>>(xc, rowscale, Wt, be, selE, selW, step_out[t]);
  }
}

// Round 4
// 492.953 us; speedup vs baseline: 7.3653x; 1.1888x over previous
//
#include <hip/hip_runtime.h>

typedef __attribute__((ext_vector_type(8))) short bf16x8;
typedef __attribute__((ext_vector_type(4))) float f32x4;

#define CC 256
#define SS 1024
#define KK 4
#define XR 6
#define XC 34
#define KP 40   // xs stride (ushorts)
#define KPB 36  // Bl stride (ushorts)

__device__ __forceinline__ unsigned int f2bf(float v) {
  unsigned int u = __float_as_uint(v);
  return (u + 0x7FFFu + ((u >> 16) & 1u)) >> 16;
}

// qk[c][n] = sum_d Wk[c, n*64+d] * q[n, d]
__global__ void qk_kernel(const float* __restrict__ Wk, const float* __restrict__ q,
                          float* __restrict__ qk) {
  int t = blockIdx.x * blockDim.x + threadIdx.x;
  if (t >= CC * 2) return;
  int c = t >> 1, n = t & 1;
  float s = 0.f;
  for (int d = 0; d < 64; ++d) s += Wk[c * 128 + n * 64 + d] * q[n * 64 + d];
  qk[c * 2 + n] = s;
}

// scores[b][n][s] = (x[b,s,:] . qk[:,n]) / 8   (one wave per pixel)
__global__ void scores_kernel(const float* __restrict__ x, const float* __restrict__ qk,
                              float* __restrict__ attn) {
  int wave = threadIdx.x >> 6, lane = threadIdx.x & 63;
  int pix = blockIdx.x * 4 + wave;
  int b = pix >> 10, s = pix & 1023;
  const float4 xv = *(const float4*)(x + (size_t)pix * CC + lane * 4);
  float d0 = 0.f, d1 = 0.f;
  const float* xp = (const float*)&xv;
#pragma unroll
  for (int j = 0; j < 4; ++j) {
    float xc = xp[j];
    d0 += xc * qk[(lane * 4 + j) * 2 + 0];
    d1 += xc * qk[(lane * 4 + j) * 2 + 1];
  }
#pragma unroll
  for (int m = 32; m >= 1; m >>= 1) {
    d0 += __shfl_xor(d0, m, 64);
    d1 += __shfl_xor(d1, m, 64);
  }
  if (lane == 0) {
    attn[((size_t)b * 2 + 0) * SS + s] = d0 * 0.125f;
    attn[((size_t)b * 2 + 1) * SS + s] = d1 * 0.125f;
  }
}

// block per batch: softmax both heads in-place + rowscale
__global__ void softmax_rs_kernel(float* __restrict__ attn, const float* __restrict__ alpha,
                                  float* __restrict__ rowscale) {
  __shared__ float red0[4], red1[4];
  int b = blockIdx.x, tid = threadIdx.x;
  float* p0 = attn + (size_t)b * 2048;
  float* p1 = p0 + 1024;
  float4 v0 = *(float4*)(p0 + tid * 4);
  float4 v1 = *(float4*)(p1 + tid * 4);
  float m0 = fmaxf(fmaxf(v0.x, v0.y), fmaxf(v0.z, v0.w));
  float m1 = fmaxf(fmaxf(v1.x, v1.y), fmaxf(v1.z, v1.w));
#pragma unroll
  for (int sh = 32; sh >= 1; sh >>= 1) {
    m0 = fmaxf(m0, __shfl_xor(m0, sh, 64));
    m1 = fmaxf(m1, __shfl_xor(m1, sh, 64));
  }
  if ((tid & 63) == 0) { red0[tid >> 6] = m0; red1[tid >> 6] = m1; }
  __syncthreads();
  m0 = fmaxf(fmaxf(red0[0], red0[1]), fmaxf(red0[2], red0[3]));
  m1 = fmaxf(fmaxf(red1[0], red1[1]), fmaxf(red1[2], red1[3]));
  float4 e0, e1;
  e0.x = expf(v0.x - m0); e0.y = expf(v0.y - m0); e0.z = expf(v0.z - m0); e0.w = expf(v0.w - m0);
  e1.x = expf(v1.x - m1); e1.y = expf(v1.y - m1); e1.z = expf(v1.z - m1); e1.w = expf(v1.w - m1);
  float s0 = e0.x + e0.y + e0.z + e0.w;
  float s1 = e1.x + e1.y + e1.z + e1.w;
#pragma unroll
  for (int sh = 32; sh >= 1; sh >>= 1) {
    s0 += __shfl_xor(s0, sh, 64);
    s1 += __shfl_xor(s1, sh, 64);
  }
  __syncthreads();
  if ((tid & 63) == 0) { red0[tid >> 6] = s0; red1[tid >> 6] = s1; }
  __syncthreads();
  s0 = red0[0] + red0[1] + red0[2] + red0[3];
  s1 = red1[0] + red1[1] + red1[2] + red1[3];
  float i0 = 1.f / s0, i1 = 1.f / s1;
  e0.x *= i0; e0.y *= i0; e0.z *= i0; e0.w *= i0;
  e1.x *= i1; e1.y *= i1; e1.z *= i1; e1.w *= i1;
  *(float4*)(p0 + tid * 4) = e0;
  *(float4*)(p1 + tid * 4) = e1;
  float al = alpha[0];
  float a = (al > 20.f) ? al : log1pf(expf(al));
  float k = 0.5f * 1024.f * a;
  float4 rs;
  rs.x = 1.f + (e0.x + e1.x) * k;
  rs.y = 1.f + (e0.y + e1.y) * k;
  rs.z = 1.f + (e0.z + e1.z) * k;
  rs.w = 1.f + (e0.w + e1.w) * k;
  *(float4*)(rowscale + (size_t)b * 1024 + tid * 4) = rs;
}

// partial xa over 64-s chunks: xa_part[b][ch][n][c]
__global__ void xa_part_kernel(const float* __restrict__ x, const float* __restrict__ attn,
                               float* __restrict__ xa_part) {
  int ch = blockIdx.x, b = blockIdx.y, c = threadIdx.x;
  int s0 = ch * 64;
  const float* a0 = attn + (size_t)b * 2048 + s0;
  const float* a1 = a0 + 1024;
  const float* xb = x + ((size_t)b * 1024 + s0) * CC + c;
  float acc0 = 0.f, acc1 = 0.f;
  for (int i = 0; i < 64; ++i) {
    float xv = xb[(size_t)i * CC];
    acc0 += a0[i] * xv;
    acc1 += a1[i] * xv;
  }
  float* o = xa_part + ((size_t)b * 16 + ch) * 512;
  o[c] = acc0;
  o[256 + c] = acc1;
}

// reduce xa_part -> pooled -> logits -> top-2 routing
__global__ void route_kernel(const float* __restrict__ xa_part, const float* __restrict__ Wv,
                             const float* __restrict__ Wmlp, float* __restrict__ allowed,
                             int* __restrict__ selE, float* __restrict__ selW, int step) {
  __shared__ float xs[512];
  __shared__ float pooled[128];
  __shared__ float lg[4];
  int b = blockIdx.x, tid = threadIdx.x;
#pragma unroll
  for (int i = 0; i < 2; ++i) {
    int id = tid + i * 256;
    float s = 0.f;
    for (int ch = 0; ch < 16; ++ch) s += xa_part[((size_t)b * 16 + ch) * 512 + id];
    xs[id] = s;
  }
  __syncthreads();
  if (tid < 128) {
    int n = tid >> 6;
    float s = 0.f;
    const float* xr = xs + n * 256;
    for (int c = 0; c < 256; ++c) s += xr[c] * Wv[(size_t)c * 128 + tid];
    pooled[tid] = s;
  }
  __syncthreads();
  if (tid < 4) {
    float s = 0.f;
    for (int d = 0; d < 128; ++d) s += pooled[d] * Wmlp[d * 4 + tid];
    lg[tid] = s;
  }
  __syncthreads();
  if (tid == 0) {
    float al[KK];
    if (step == 0) { for (int k = 0; k < KK; ++k) al[k] = 1.f; }
    else           { for (int k = 0; k < KK; ++k) al[k] = allowed[b * KK + k]; }
    float ml[KK];
    for (int k = 0; k < KK; ++k)
      ml[k] = (al[k] > 0.5f) ? lg[k] * (1.f / 1.5f) : (-1e9f) * (1.f / 1.5f);
    float m = ml[0];
    for (int k = 1; k < KK; ++k) m = fmaxf(m, ml[k]);
    float e[KK], ssum = 0.f;
    for (int k = 0; k < KK; ++k) { e[k] = expf(ml[k] - m); ssum += e[k]; }
    float w[KK];
    for (int k = 0; k < KK; ++k) w[k] = e[k] / ssum;
    int i0 = 0;
    for (int k = 1; k < KK; ++k) if (w[k] > w[i0]) i0 = k;
    int i1 = -1;
    for (int k = 0; k < KK; ++k) {
      if (k == i0) continue;
      if (i1 < 0 || w[k] > w[i1]) i1 = k;
    }
    float denom = w[i0] + w[i1] + 1e-9f;
    selE[b * 2 + 0] = i0;
    selE[b * 2 + 1] = i1;
    selW[b * 2 + 0] = w[i0] / denom;
    selW[b * 2 + 1] = w[i1] / denom;
    if (i0 != KK - 1) al[i0] = fminf(fmaxf(al[i0] - 1.f, 0.f), 1.f);
    al[KK - 1] = fmaxf(al[KK - 1], 1.f);
    for (int k = 0; k < KK; ++k) allowed[b * KK + k] = al[k];
  }
}

// Per-batch combined expert weights (exact f32 combine), split to bf16 hi/lo,
// transposed layout: Wc_{h,l}[(b*72 + tap*8 + kc)*8192 + co*32 + ki]
__global__ void combine_w_kernel(const float* __restrict__ We,
                                 const int* __restrict__ selE, const float* __restrict__ selW,
                                 unsigned short* __restrict__ Wc_h,
                                 unsigned short* __restrict__ Wc_l) {
  int tile = blockIdx.x;  // 0..71 = tap*8+kc
  int b = blockIdx.y;
  int tap = tile >> 3, kc = tile & 7;
  int co = threadIdx.x;
  int e0 = selE[b * 2], e1 = selE[b * 2 + 1];
  float w0 = selW[b * 2], w1 = selW[b * 2 + 1];
  __shared__ float ts[32][257];
  const float* s0 = We + (size_t)(e0 * 9 + tap) * 65536 + (size_t)(kc * 32) * 256 + co;
  const float* s1 = We + (size_t)(e1 * 9 + tap) * 65536 + (size_t)(kc * 32) * 256 + co;
  for (int ci = 0; ci < 32; ++ci)
    ts[ci][co] = w0 * s0[(size_t)ci * 256] + w1 * s1[(size_t)ci * 256];
  __syncthreads();
  __align__(16) unsigned short hh[32];
  __align__(16) unsigned short ll[32];
#pragma unroll
  for (int ki = 0; ki < 32; ++ki) {
    float v = ts[ki][co];
    unsigned int h = f2bf(v);
    unsigned int l = f2bf(v - __uint_as_float(h << 16));
    hh[ki] = (unsigned short)h;
    ll[ki] = (unsigned short)l;
  }
  size_t base = ((size_t)b * 72 + tile) * 8192 + (size_t)co * 32;
#pragma unroll
  for (int j = 0; j < 4; ++j) {
    *(uint4*)(Wc_h + base + j * 8) = *(const uint4*)(hh + j * 8);
    *(uint4*)(Wc_l + base + j * 8) = *(const uint4*)(ll + j * 8);
  }
}

// MFMA implicit-GEMM conv, precombined weights. Block = 512 thr (8 waves),
// M=128 pixels (4 rows + halo), N=128 cos. 3 split-bf16 terms, f32 accum.
// B-tile double-buffered in LDS -> single barrier per K-step.
__global__ __launch_bounds__(512, 4) void conv_kernel(
    const float* __restrict__ xin, const float* __restrict__ rowscale,
    const unsigned short* __restrict__ Wc_h, const unsigned short* __restrict__ Wc_l,
    const float* __restrict__ be,
    const int* __restrict__ selE, const float* __restrict__ selW,
    float* __restrict__ out) {
  __shared__ unsigned short xs_h[XR * XC * KP];
  __shared__ unsigned short xs_l[XR * XC * KP];
  __shared__ unsigned short Bl[2][2 * 128 * KPB];
  __shared__ float rs_lds[XR * XC];

  int b = blockIdx.y;
  int mt = blockIdx.x >> 1, nt = blockIdx.x & 1;
  int h0 = mt * 4;
  int tid = threadIdx.x;
  int lane = tid & 63, wid = tid >> 6;
  int wm = wid >> 2, wn = wid & 3;
  int l15 = lane & 15, kl = lane >> 4;

  int e0 = selE[b * 2], e1 = selE[b * 2 + 1];
  float w0 = selW[b * 2], w1 = selW[b * 2 + 1];

  if (tid < XR * XC) {
    int r = tid / XC, c = tid - r * XC;
    int gr = h0 - 1 + r, gc = c - 1;
    float v = 0.f;
    if (gr >= 0 && gr < 32 && gc >= 0 && gc < 32)
      v = rowscale[(size_t)b * 1024 + gr * 32 + gc];
    rs_lds[tid] = v;
  }

  int prow[4], pcb[4];
#pragma unroll
  for (int mf = 0; mf < 4; ++mf) {
    int pm = wm * 64 + mf * 16;
    prow[mf] = pm >> 5;
    pcb[mf] = pm & 31;
  }
  int bidx[2];
#pragma unroll
  for (int nf = 0; nf < 2; ++nf) bidx[nf] = (wn * 32 + nf * 16 + l15) * KPB + kl * 8;

  int con = nt * 128 + wn * 32 + l15;
  float bias[2];
#pragma unroll
  for (int nf = 0; nf < 2; ++nf)
    bias[nf] = w0 * be[e0 * 256 + con + nf * 16] + w1 * be[e1 * 256 + con + nf * 16];

  f32x4 acc[4][2];
#pragma unroll
  for (int mf = 0; mf < 4; ++mf)
#pragma unroll
    for (int nf = 0; nf < 2; ++nf) acc[mf][nf] = (f32x4){0.f, 0.f, 0.f, 0.f};

  auto stage_x = [&](int kc) {
    for (int idx = tid; idx < XR * XC * 8; idx += 512) {
      int ki4 = idx & 7, cell = idx >> 3;
      int r = cell / XC, c = cell - r * XC;
      int gr = h0 - 1 + r, gc = c - 1;
      float4 v = make_float4(0.f, 0.f, 0.f, 0.f);
      if (gr >= 0 && gr < 32 && gc >= 0 && gc < 32)
        v = *(const float4*)(xin + (((size_t)b * 32 + gr) * 32 + gc) * 256 + kc * 32 + ki4 * 4);
      float sc = rs_lds[cell];
      float x0 = v.x * sc, x1 = v.y * sc, x2 = v.z * sc, x3 = v.w * sc;
      unsigned int h0b = f2bf(x0), h1b = f2bf(x1), h2b = f2bf(x2), h3b = f2bf(x3);
      unsigned int l0b = f2bf(x0 - __uint_as_float(h0b << 16));
      unsigned int l1b = f2bf(x1 - __uint_as_float(h1b << 16));
      unsigned int l2b = f2bf(x2 - __uint_as_float(h2b << 16));
      unsigned int l3b = f2bf(x3 - __uint_as_float(h3b << 16));
      uint2 hw = make_uint2(h0b | (h1b << 16), h2b | (h3b << 16));
      uint2 lw2 = make_uint2(l0b | (l1b << 16), l2b | (l3b << 16));
      *(uint2*)(xs_h + cell * KP + ki4 * 4) = hw;
      *(uint2*)(xs_l + cell * KP + ki4 * 4) = lw2;
    }
  };

  auto w_src = [&](const unsigned short* W, int tap, int kc) -> uint4 {
    size_t base = ((size_t)b * 72 + tap * 8 + kc) * 8192 + (size_t)nt * 4096;
    return *((const uint4*)(W + base) + tid);
  };
  int lw = (tid >> 2) * KPB + (tid & 3) * 8;
  auto write_B = [&](int buf, uint4 ph, uint4 pl) {
    *(uint4*)(&Bl[buf][lw]) = ph;
    *(uint4*)(&Bl[buf][128 * KPB + lw]) = pl;
  };

  __syncthreads();  // rs_lds ready
  stage_x(0);
  write_B(0, w_src(Wc_h, 0, 0), w_src(Wc_l, 0, 0));
  __syncthreads();

  int tap = 0, kc = 0, cur = 0;
  for (int tk = 0; tk < 72; ++tk) {
    int ntap = tap + 1, nkc = kc;
    if (ntap == 9) { ntap = 0; nkc = kc + 1; }
    bool pf = (tk < 71);
    uint4 ph, pl;
    if (pf) {
      ph = w_src(Wc_h, ntap, nkc);
      pl = w_src(Wc_l, ntap, nkc);
    }

    int dy = tap / 3;
    int dx = tap - dy * 3;
    int aoff[4];
#pragma unroll
    for (int mf = 0; mf < 4; ++mf)
      aoff[mf] = ((prow[mf] + dy) * XC + pcb[mf] + l15 + dx) * KP + kl * 8;

    bf16x8 afh[4], bfh[2], bfl[2];
#pragma unroll
    for (int mf = 0; mf < 4; ++mf) afh[mf] = *(const bf16x8*)(xs_h + aoff[mf]);
#pragma unroll
    for (int nf = 0; nf < 2; ++nf) {
      bfh[nf] = *(const bf16x8*)(&Bl[cur][bidx[nf]]);
      bfl[nf] = *(const bf16x8*)(&Bl[cur][128 * KPB + bidx[nf]]);
    }
#pragma unroll
    for (int mf = 0; mf < 4; ++mf)
#pragma unroll
      for (int nf = 0; nf < 2; ++nf)
        acc[mf][nf] = __builtin_amdgcn_mfma_f32_16x16x32_bf16(afh[mf], bfh[nf], acc[mf][nf], 0, 0, 0);
#pragma unroll
    for (int mf = 0; mf < 4; ++mf)
#pragma unroll
      for (int nf = 0; nf < 2; ++nf)
        acc[mf][nf] = __builtin_amdgcn_mfma_f32_16x16x32_bf16(afh[mf], bfl[nf], acc[mf][nf], 0, 0, 0);
    bf16x8 afl[4];
#pragma unroll
    for (int mf = 0; mf < 4; ++mf) afl[mf] = *(const bf16x8*)(xs_l + aoff[mf]);
#pragma unroll
    for (int mf = 0; mf < 4; ++mf)
#pragma unroll
      for (int nf = 0; nf < 2; ++nf)
        acc[mf][nf] = __builtin_amdgcn_mfma_f32_16x16x32_bf16(afl[mf], bfh[nf], acc[mf][nf], 0, 0, 0);

    if (pf) {
      write_B(cur ^ 1, ph, pl);
      if (nkc != kc) {
        __syncthreads();   // all xs reads for kc done
        stage_x(nkc);
      }
      __syncthreads();     // Bl[next] (+xs) visible to all
    }
    cur ^= 1;
    tap = ntap;
    kc = nkc;
  }

#pragma unroll
  for (int mf = 0; mf < 4; ++mf) {
    size_t rowbase = ((size_t)b * 32 + h0 + prow[mf]) * 32;
#pragma unroll
    for (int nf = 0; nf < 2; ++nf) {
      int co = nt * 128 + wn * 32 + nf * 16 + l15;
#pragma unroll
      for (int r = 0; r < 4; ++r) {
        int col = pcb[mf] + kl * 4 + r;
        out[(rowbase + col) * 256 + co] = acc[mf][nf][r] + bias[nf];
      }
    }
  }
}

extern "C" void kernel_launch(void* const* d_in, const int* in_sizes, int n_in,
                              void* d_out, int out_size, void* d_ws, size_t ws_size,
                              hipStream_t stream) {
  const float* x_in  = (const float*)d_in[0];
  const float* q     = (const float*)d_in[1];
  const float* Wk    = (const float*)d_in[2];
  const float* Wv    = (const float*)d_in[3];
  const float* Wmlp  = (const float*)d_in[4];
  const float* alpha = (const float*)d_in[5];
  const float* We    = (const float*)d_in[6];
  const float* be    = (const float*)d_in[7];
  float* out = (float*)d_out;
  float* ws = (float*)d_ws;

  float* qk       = ws;                 // 512
  float* attn     = qk + 512;           // 65536
  float* rowscale = attn + 65536;       // 32768
  float* xa_part  = rowscale + 32768;   // 262144
  float* allowed  = xa_part + 262144;   // 128
  float* selW     = allowed + 128;      // 64
  int*   selE     = (int*)(selW + 64);  // 64
  float* xbuf     = selW + 128;         // 8388608 floats
  unsigned short* Wc_h = (unsigned short*)(xbuf + 8388608);  // 18,874,368 ushorts
  unsigned short* Wc_l = Wc_h + (size_t)32 * 72 * 8192;      // 18,874,368 ushorts

  qk_kernel<<<2, 256, 0, stream>>>(Wk, q, qk);

  const float* step_in[3] = {x_in, out, xbuf};
  float* step_out[3] = {out, xbuf, out};

  for (int t = 0; t < 3; ++t) {
    const float* xc = step_in[t];
    scores_kernel<<<8192, 256, 0, stream>>>(xc, qk, attn);
    softmax_rs_kernel<<<32, 256, 0, stream>>>(attn, alpha, rowscale);
    xa_part_kernel<<<dim3(16, 32), 256, 0, stream>>>(xc, attn, xa_part);
    route_kernel<<<32, 256, 0, stream>>>(xa_part, Wv, Wmlp, allowed, selE, selW, t);
    combine_w_kernel<<<dim3(72, 32), 256, 0, stream>>>(We, selE, selW, Wc_h, Wc_l);
    conv_kernel<<<dim3(16, 32), 512, 0, stream>>>(xc, rowscale, Wc_h, Wc_l, be, selE, selW, step_out[t]);
  }
}